// Round 1
// baseline (758.707 us; speedup 1.0000x reference)
//
#include <hip/hip_runtime.h>

typedef short short8 __attribute__((ext_vector_type(8)));
typedef short short4v __attribute__((ext_vector_type(4)));
typedef float floatx4 __attribute__((ext_vector_type(4)));
typedef unsigned short ushort_t;
typedef unsigned int uint_t;

#define DI __device__ __forceinline__

DI ushort_t f2bf(float f) {
  uint_t u = __builtin_bit_cast(uint_t, f);
  uint_t r = u + 0x7FFFu + ((u >> 16) & 1u);
  return (ushort_t)(r >> 16);
}

DI floatx4 mfma16(short8 a, short8 b, floatx4 c) {
  return __builtin_amdgcn_mfma_f32_16x16x32_bf16(a, b, c, 0, 0, 0);
}

DI void async16(const void* g, void* l) {
  __builtin_amdgcn_global_load_lds(
      (__attribute__((address_space(1))) void*)(g),
      (__attribute__((address_space(3))) void*)(l), 16, 0, 0);
}

// ---------------- f32 -> bf16 conversion, 8 elems/thread ----------------
__global__ __launch_bounds__(256)
void k_f2bf(const float* __restrict__ in, ushort_t* __restrict__ out, long n)
{
  const long i = ((long)blockIdx.x * 256 + threadIdx.x) * 8;
  if (i >= n) return;
  const float4 a = *(const float4*)(in + i);
  const float4 b = *(const float4*)(in + i + 4);
  union { short8 s; ushort_t u[8]; } o;
  o.u[0] = f2bf(a.x); o.u[1] = f2bf(a.y); o.u[2] = f2bf(a.z); o.u[3] = f2bf(a.w);
  o.u[4] = f2bf(b.x); o.u[5] = f2bf(b.y); o.u[6] = f2bf(b.z); o.u[7] = f2bf(b.w);
  *(short8*)(out + i) = o.s;
}

// ---------------- GEMM: C[M,N] = A[M,K] * B[N,K]^T, bf16 in, 128x128 tile ----------------
// out = (acc + bias[n]) * out_scale; OUT_BF16 ? bf16 : f32 store.
template<int OUT_BF16>
__global__ __launch_bounds__(256)
void k_gemm(const ushort_t* __restrict__ A, const ushort_t* __restrict__ B,
            const float* __restrict__ bias, void* __restrict__ Cout,
            int N, int K, float out_scale)
{
  __shared__ ushort_t As[128 * 32];
  __shared__ ushort_t Bs[128 * 32];
  const int tid = threadIdx.x;
  const int w = tid >> 6, l = tid & 63;
  const int wm = w >> 1, wn = w & 1;      // 2x2 waves, each 64x64 output
  const int lr = l & 15, lg = l >> 4;
  const long m0 = (long)blockIdx.y * 128;
  const long n0 = (long)blockIdx.x * 128;

  const floatx4 fz = {0.f, 0.f, 0.f, 0.f};
  floatx4 acc[4][4];
#pragma unroll
  for (int i = 0; i < 4; ++i)
#pragma unroll
    for (int j = 0; j < 4; ++j) acc[i][j] = fz;

  // staging: chunk c in [0,512): row=c>>2, col=(c&3)*8 ; LDS flat byte = c*16
  const int c0 = tid, c1 = 256 + tid;
  const ushort_t* gA0 = A + (m0 + (c0 >> 2)) * K + ((c0 & 3) << 3);
  const ushort_t* gA1 = A + (m0 + (c1 >> 2)) * K + ((c1 & 3) << 3);
  const ushort_t* gB0 = B + (n0 + (c0 >> 2)) * K + ((c0 & 3) << 3);
  const ushort_t* gB1 = B + (n0 + (c1 >> 2)) * K + ((c1 & 3) << 3);
  ushort_t* lA0 = &As[(0 * 256 + w * 64) * 8];
  ushort_t* lA1 = &As[(1 * 256 + w * 64) * 8];
  ushort_t* lB0 = &Bs[(0 * 256 + w * 64) * 8];
  ushort_t* lB1 = &Bs[(1 * 256 + w * 64) * 8];

  const int nK = K >> 5;
  for (int kt = 0; kt < nK; ++kt) {
    const int ko = kt << 5;
    __syncthreads();
    async16(gA0 + ko, lA0);
    async16(gA1 + ko, lA1);
    async16(gB0 + ko, lB0);
    async16(gB1 + ko, lB1);
    __syncthreads();
    short8 a[4], b[4];
#pragma unroll
    for (int i = 0; i < 4; ++i)
      a[i] = *(const short8*)&As[(wm * 64 + i * 16 + lr) * 32 + lg * 8];
#pragma unroll
    for (int j = 0; j < 4; ++j)
      b[j] = *(const short8*)&Bs[(wn * 64 + j * 16 + lr) * 32 + lg * 8];
#pragma unroll
    for (int i = 0; i < 4; ++i)
#pragma unroll
      for (int j = 0; j < 4; ++j)
        acc[i][j] = mfma16(a[i], b[j], acc[i][j]);
  }

#pragma unroll
  for (int j = 0; j < 4; ++j) {
    const long gn = n0 + wn * 64 + j * 16 + lr;
    const float bv = bias[gn];
#pragma unroll
    for (int i = 0; i < 4; ++i) {
      const long gm = m0 + wm * 64 + i * 16 + lg * 4;
#pragma unroll
      for (int r = 0; r < 4; ++r) {
        const float v = (acc[i][j][r] + bv) * out_scale;
        if (OUT_BF16) ((ushort_t*)Cout)[(gm + r) * N + gn] = f2bf(v);
        else          ((float*)Cout)[(gm + r) * N + gn] = v;
      }
    }
  }
}

// ---------------- V transpose: KV[b,t,kh,{k,v},d] -> Vt[b,kh,d,t] ----------------
__global__ __launch_bounds__(256)
void k_transv(const ushort_t* __restrict__ KV, ushort_t* __restrict__ Vt)
{
  const int tblk = blockIdx.x, kh = blockIdx.y, b = blockIdx.z;
  const int tid = threadIdx.x;
#pragma unroll
  for (int j = 0; j < 4; ++j) {
    const int c = j * 256 + tid;            // 1024 chunks: d = c>>3, t0 = (c&7)*8
    const int d = c >> 3, t0 = (c & 7) << 3;
    const ushort_t* src = KV + (long)(b * 1024 + tblk * 64 + t0) * 1024 + kh * 256 + 128 + d;
    union { short8 s; ushort_t u[8]; } vv;
#pragma unroll
    for (int i = 0; i < 8; ++i) vv.u[i] = src[(long)i * 1024];
    *(short8*)(Vt + ((long)(b * 4 + kh) * 128 + d) * 1024 + tblk * 64 + t0) = vv.s;
  }
}

// ---------------- Flash attention (causal, GQA) ----------------
// Q: (B*T, 2048) bf16 pre-scaled by 1/sqrt(128); KV: (B*T, 1024) bf16;
// Vt: (B*4, 128, 1024) bf16; Y: (B*T, 2048) bf16.
// Block = (qt, h, b): 64 q-rows; 4 waves x 16 q-rows; KV tiles of 64.
__global__ __launch_bounds__(256)
void k_attn(const ushort_t* __restrict__ Q, const ushort_t* __restrict__ KV,
            const ushort_t* __restrict__ Vt, ushort_t* __restrict__ Y)
{
  __shared__ __align__(16) ushort_t Pl[4][16][72];   // per-wave P tile, padded stride 72
  const int tid = threadIdx.x;
  const int w = tid >> 6, l = tid & 63;
  const int lr = l & 15, lg = l >> 4;
  const int qt = blockIdx.x, h = blockIdx.y, b = blockIdx.z;
  const int kh = h >> 2;
  const int qrow = qt * 64 + w * 16;

  const ushort_t* qptr = Q + ((long)(b * 1024 + qrow + lr)) * 2048 + h * 128 + lg * 8;
  short8 qf[4];
#pragma unroll
  for (int c = 0; c < 4; ++c) qf[c] = *(const short8*)(qptr + c * 32);

  float m_s = -__builtin_inff(), l_s = 0.f;
  const floatx4 fz = {0.f, 0.f, 0.f, 0.f};
  floatx4 yacc[8];
#pragma unroll
  for (int dt = 0; dt < 8; ++dt) yacc[dt] = fz;

  const ushort_t* kbase = KV + (long)b * 1024 * 1024 + kh * 256 + lg * 8;
  const ushort_t* vbase = Vt + ((long)(b * 4 + kh) * 128 + lr) * 1024;

  for (int t = 0; t <= qt; ++t) {
    // fence: previous tile's P ds_reads must complete before this tile's P ds_writes
    __asm__ volatile("s_waitcnt lgkmcnt(0)" ::: "memory");
    // S^T = K * Q^T : lane holds q = lr, k = t*64 + k2*16 + lg*4 + r
    floatx4 st[4];
#pragma unroll
    for (int k2 = 0; k2 < 4; ++k2) {
      floatx4 s = fz;
      const ushort_t* kp = kbase + (long)(t * 64 + k2 * 16 + lr) * 1024;
#pragma unroll
      for (int c = 0; c < 4; ++c) {
        const short8 kf = *(const short8*)(kp + c * 32);
        s = mfma16(kf, qf[c], s);
      }
      st[k2] = s;
    }
    if (t == qt) {  // causal mask on diagonal tile
      const int qg = qrow + lr;
#pragma unroll
      for (int k2 = 0; k2 < 4; ++k2)
#pragma unroll
        for (int r = 0; r < 4; ++r)
          if (t * 64 + k2 * 16 + lg * 4 + r > qg) st[k2][r] = -__builtin_inff();
    }
    // online softmax (stats live at q = lr, replicated across the 4 lane-groups)
    float pm = -__builtin_inff();
#pragma unroll
    for (int k2 = 0; k2 < 4; ++k2)
      pm = fmaxf(pm, fmaxf(fmaxf(st[k2][0], st[k2][1]), fmaxf(st[k2][2], st[k2][3])));
    pm = fmaxf(pm, __shfl_xor(pm, 16));
    pm = fmaxf(pm, __shfl_xor(pm, 32));
    const float m_new = fmaxf(m_s, pm);
    const float corr = __expf(m_s - m_new);
    float psum = 0.f;
#pragma unroll
    for (int k2 = 0; k2 < 4; ++k2) {
      union { short4v v; ushort_t u[4]; } pk;
#pragma unroll
      for (int r = 0; r < 4; ++r) {
        const float p = __expf(st[k2][r] - m_new);
        psum += p;
        pk.u[r] = f2bf(p);
      }
      *(short4v*)&Pl[w][lr][k2 * 16 + lg * 4] = pk.v;
    }
    psum += __shfl_xor(psum, 16);
    psum += __shfl_xor(psum, 32);
    l_s = l_s * corr + psum;
    m_s = m_new;
    // rescale accumulator (PV layout: q = lg*4 + r)
    const float cc0 = __shfl(corr, lg * 4 + 0);
    const float cc1 = __shfl(corr, lg * 4 + 1);
    const float cc2 = __shfl(corr, lg * 4 + 2);
    const float cc3 = __shfl(corr, lg * 4 + 3);
#pragma unroll
    for (int dt = 0; dt < 8; ++dt) {
      yacc[dt][0] *= cc0; yacc[dt][1] *= cc1;
      yacc[dt][2] *= cc2; yacc[dt][3] *= cc3;
    }
    // fence: P ds_writes complete before P ds_reads (cross-lane, in-wave)
    __asm__ volatile("s_waitcnt lgkmcnt(0)" ::: "memory");
    // PV: y[q][d] += P[q][k] V[k][d]; V frags contiguous from Vt
#pragma unroll
    for (int kc = 0; kc < 2; ++kc) {
      const short8 pf = *(const short8*)&Pl[w][lr][kc * 32 + lg * 8];
      const ushort_t* vp = vbase + t * 64 + kc * 32 + lg * 8;
#pragma unroll
      for (int dt = 0; dt < 8; ++dt) {
        const short8 vf = *(const short8*)(vp + (long)dt * 16 * 1024);
        yacc[dt] = mfma16(pf, vf, yacc[dt]);
      }
    }
  }

  const float linv = 1.f / l_s;
  const float i0 = __shfl(linv, lg * 4 + 0);
  const float i1 = __shfl(linv, lg * 4 + 1);
  const float i2 = __shfl(linv, lg * 4 + 2);
  const float i3 = __shfl(linv, lg * 4 + 3);
  ushort_t* yp = Y + ((long)(b * 1024 + qrow)) * 2048 + h * 128 + lr;
#pragma unroll
  for (int dt = 0; dt < 8; ++dt) {
    yp[(long)(lg * 4 + 0) * 2048 + dt * 16] = f2bf(yacc[dt][0] * i0);
    yp[(long)(lg * 4 + 1) * 2048 + dt * 16] = f2bf(yacc[dt][1] * i1);
    yp[(long)(lg * 4 + 2) * 2048 + dt * 16] = f2bf(yacc[dt][2] * i2);
    yp[(long)(lg * 4 + 3) * 2048 + dt * 16] = f2bf(yacc[dt][3] * i3);
  }
}

// ---------------- launch ----------------
extern "C" void kernel_launch(void* const* d_in, const int* in_sizes, int n_in,
                              void* d_out, int out_size, void* d_ws, size_t ws_size,
                              hipStream_t stream)
{
  (void)in_sizes; (void)n_in; (void)out_size;
  const float* x   = (const float*)d_in[0];
  const float* Wq  = (const float*)d_in[1];
  const float* bq  = (const float*)d_in[2];
  const float* Wkv = (const float*)d_in[3];
  const float* bkv = (const float*)d_in[4];
  const float* Wo  = (const float*)d_in[5];
  const float* bo  = (const float*)d_in[6];
  float* out = (float*)d_out;
  char* ws = (char*)d_ws;

  if (ws_size < 104857600) return;  // need 100 MB

  const long NX = 8192L * 2048, NWQ = 2048L * 2048, NWKV = 1024L * 2048, NWO = 2048L * 2048;
  ushort_t* xb   = (ushort_t*)(ws);              // 32MB; reused as Y after KV GEMM
  ushort_t* Qb   = (ushort_t*)(ws + 33554432);   // 32MB
  ushort_t* KVb  = (ushort_t*)(ws + 67108864);   // 16MB
  ushort_t* Wqb  = (ushort_t*)(ws + 83886080);   // 8MB; reused as Vt after Q GEMM
  ushort_t* Wkvb = (ushort_t*)(ws + 92274688);   // 4MB
  ushort_t* Wob  = (ushort_t*)(ws + 96468992);   // 8MB
  ushort_t* Vtb  = Wqb;
  ushort_t* Yb   = xb;

  k_f2bf<<<dim3(NX   / 2048), 256, 0, stream>>>(x,   xb,   NX);
  k_f2bf<<<dim3(NWQ  / 2048), 256, 0, stream>>>(Wq,  Wqb,  NWQ);
  k_f2bf<<<dim3(NWKV / 2048), 256, 0, stream>>>(Wkv, Wkvb, NWKV);
  k_f2bf<<<dim3(NWO  / 2048), 256, 0, stream>>>(Wo,  Wob,  NWO);

  const float scale = 0.08838834764831845f;  // 1/sqrt(128), folded into Q
  k_gemm<1><<<dim3(16, 64), 256, 0, stream>>>(xb, Wqb,  bq,  Qb,  2048, 2048, scale);
  k_gemm<1><<<dim3(8,  64), 256, 0, stream>>>(xb, Wkvb, bkv, KVb, 1024, 2048, 1.0f);
  k_transv<<<dim3(16, 4, 8), 256, 0, stream>>>(KVb, Vtb);
  k_attn<<<dim3(16, 16, 8), 256, 0, stream>>>(Qb, KVb, Vtb, Yb);
  k_gemm<0><<<dim3(16, 64), 256, 0, stream>>>(Yb, Wob, bo, out, 2048, 2048, 1.0f);
}

// Round 4
// 412.853 us; speedup vs baseline: 1.8377x; 1.8377x over previous
//
#include <hip/hip_runtime.h>

typedef short short8 __attribute__((ext_vector_type(8)));
typedef short short4v __attribute__((ext_vector_type(4)));
typedef float floatx4 __attribute__((ext_vector_type(4)));
typedef unsigned short ushort_t;
typedef unsigned int uint_t;

#define DI __device__ __forceinline__

DI ushort_t f2bf(float f) {
  uint_t u = __builtin_bit_cast(uint_t, f);
  uint_t r = u + 0x7FFFu + ((u >> 16) & 1u);
  return (ushort_t)(r >> 16);
}

DI floatx4 mfma16(short8 a, short8 b, floatx4 c) {
  return __builtin_amdgcn_mfma_f32_16x16x32_bf16(a, b, c, 0, 0, 0);
}

DI void async16(const void* g, void* l) {
  __builtin_amdgcn_global_load_lds(
      (__attribute__((address_space(1))) void*)(g),
      (__attribute__((address_space(3))) void*)(l), 16, 0, 0);
}

// compiler memory fence (zero instructions) — pins memory ops across raw s_barrier
DI void cfence() { asm volatile("" ::: "memory"); }

// ---------------- f32 -> bf16 conversion, 8 elems/thread ----------------
__global__ __launch_bounds__(256)
void k_f2bf(const float* __restrict__ in, ushort_t* __restrict__ out, long n)
{
  const long i = ((long)blockIdx.x * 256 + threadIdx.x) * 8;
  if (i >= n) return;
  const float4 a = *(const float4*)(in + i);
  const float4 b = *(const float4*)(in + i + 4);
  union { short8 s; ushort_t u[8]; } o;
  o.u[0] = f2bf(a.x); o.u[1] = f2bf(a.y); o.u[2] = f2bf(a.z); o.u[3] = f2bf(a.w);
  o.u[4] = f2bf(b.x); o.u[5] = f2bf(b.y); o.u[6] = f2bf(b.z); o.u[7] = f2bf(b.w);
  *(short8*)(out + i) = o.s;
}

// ---------------- GEMM: C[M,N] = A[M,K] * B[N,K]^T, bf16 in, 128x128 tile ----------------
template<int OUT_BF16>
__global__ __launch_bounds__(256)
void k_gemm(const ushort_t* __restrict__ A, const ushort_t* __restrict__ B,
            const float* __restrict__ bias, void* __restrict__ Cout,
            int N, int K, float out_scale)
{
  __shared__ ushort_t As[128 * 32];
  __shared__ ushort_t Bs[128 * 32];
  const int tid = threadIdx.x;
  const int w = tid >> 6, l = tid & 63;
  const int wm = w >> 1, wn = w & 1;
  const int lr = l & 15, lg = l >> 4;
  const long m0 = (long)blockIdx.y * 128;
  const long n0 = (long)blockIdx.x * 128;

  const floatx4 fz = {0.f, 0.f, 0.f, 0.f};
  floatx4 acc[4][4];
#pragma unroll
  for (int i = 0; i < 4; ++i)
#pragma unroll
    for (int j = 0; j < 4; ++j) acc[i][j] = fz;

  const int c0 = tid, c1 = 256 + tid;
  const ushort_t* gA0 = A + (m0 + (c0 >> 2)) * K + ((c0 & 3) << 3);
  const ushort_t* gA1 = A + (m0 + (c1 >> 2)) * K + ((c1 & 3) << 3);
  const ushort_t* gB0 = B + (n0 + (c0 >> 2)) * K + ((c0 & 3) << 3);
  const ushort_t* gB1 = B + (n0 + (c1 >> 2)) * K + ((c1 & 3) << 3);
  ushort_t* lA0 = &As[(0 * 256 + w * 64) * 8];
  ushort_t* lA1 = &As[(1 * 256 + w * 64) * 8];
  ushort_t* lB0 = &Bs[(0 * 256 + w * 64) * 8];
  ushort_t* lB1 = &Bs[(1 * 256 + w * 64) * 8];

  const int nK = K >> 5;
  for (int kt = 0; kt < nK; ++kt) {
    const int ko = kt << 5;
    __syncthreads();
    async16(gA0 + ko, lA0);
    async16(gA1 + ko, lA1);
    async16(gB0 + ko, lB0);
    async16(gB1 + ko, lB1);
    __syncthreads();
    short8 a[4], b[4];
#pragma unroll
    for (int i = 0; i < 4; ++i)
      a[i] = *(const short8*)&As[(wm * 64 + i * 16 + lr) * 32 + lg * 8];
#pragma unroll
    for (int j = 0; j < 4; ++j)
      b[j] = *(const short8*)&Bs[(wn * 64 + j * 16 + lr) * 32 + lg * 8];
#pragma unroll
    for (int i = 0; i < 4; ++i)
#pragma unroll
      for (int j = 0; j < 4; ++j)
        acc[i][j] = mfma16(a[i], b[j], acc[i][j]);
  }

#pragma unroll
  for (int j = 0; j < 4; ++j) {
    const long gn = n0 + wn * 64 + j * 16 + lr;
    const float bv = bias[gn];
#pragma unroll
    for (int i = 0; i < 4; ++i) {
      const long gm = m0 + wm * 64 + i * 16 + lg * 4;
#pragma unroll
      for (int r = 0; r < 4; ++r) {
        const float v = (acc[i][j][r] + bv) * out_scale;
        if (OUT_BF16) ((ushort_t*)Cout)[(gm + r) * N + gn] = f2bf(v);
        else          ((float*)Cout)[(gm + r) * N + gn] = v;
      }
    }
  }
}

// ---------------- V transpose: KV[b,t,kh,{k,v},d] -> Vt[b,kh,d,t] ----------------
__global__ __launch_bounds__(256)
void k_transv(const ushort_t* __restrict__ KV, ushort_t* __restrict__ Vt)
{
  const int tblk = blockIdx.x, kh = blockIdx.y, b = blockIdx.z;
  const int tid = threadIdx.x;
#pragma unroll
  for (int j = 0; j < 4; ++j) {
    const int c = j * 256 + tid;
    const int d = c >> 3, t0 = (c & 7) << 3;
    const ushort_t* src = KV + (long)(b * 1024 + tblk * 64 + t0) * 1024 + kh * 256 + 128 + d;
    union { short8 s; ushort_t u[8]; } vv;
#pragma unroll
    for (int i = 0; i < 8; ++i) vv.u[i] = src[(long)i * 1024];
    *(short8*)(Vt + ((long)(b * 4 + kh) * 128 + d) * 1024 + tblk * 64 + t0) = vv.s;
  }
}

// ---------------- Flash attention (causal, GQA), LDS-staged + counted vmcnt ----------------
// K tile: LDS [2][64][128] XOR-swizzled, double-buffered. V tile: LDS [2][128][64]
// d-major, double-buffered. Both staged by global_load_lds with pre-swizzled SOURCE
// granules (linear LDS dest, m173 pattern).
// Race-freedom invariant (runtime, not scheduling): every wave executes
// s_waitcnt lgkmcnt(0) at the P-fence, draining ALL its prior DS reads (incl. last
// tile's PV reads), BEFORE barrier B; every DMA that overwrites a K/V buffer is
// issued AFTER a later barrier B. So writer-issue and reader-completion are
// separated by a barrier regardless of instruction scheduling.
__global__ __launch_bounds__(256)
void k_attn(const ushort_t* __restrict__ Q, const ushort_t* __restrict__ KV,
            const ushort_t* __restrict__ Vt, ushort_t* __restrict__ Y)
{
  __shared__ __align__(16) ushort_t Kl[2][64 * 128];   // 32 KB
  __shared__ __align__(16) ushort_t Vl[2][128 * 64];   // 32 KB
  __shared__ __align__(16) ushort_t Pl[4][16][72];     // 9.2 KB
  const int tid = threadIdx.x;
  const int w = tid >> 6, l = tid & 63;
  const int lr = l & 15, lg = l >> 4;
  // remap: batch b pinned per XCD (K+V 2MB fits 4MB L2); long diagonals first
  const int p = blockIdx.x;
  const int v = ((p & 7) << 8) | (p >> 3);
  const int b = v >> 8;
  const int kh = (v >> 6) & 3;
  const int hs = (v >> 4) & 3;
  const int qt = 15 - (v & 15);
  const int h = kh * 4 + hs;
  const int qrow = qt * 64 + w * 16;

  const ushort_t* qptr = Q + ((long)(b * 1024 + qrow + lr)) * 2048 + h * 128 + lg * 8;
  short8 qf[4];
#pragma unroll
  for (int c = 0; c < 4; ++c) qf[c] = *(const short8*)(qptr + c * 32);

  // staging source pointers (pre-swizzled granules) + linear LDS offsets
  const ushort_t* kg[4];
  const ushort_t* vg[4];
  int ld[4];
#pragma unroll
  for (int i = 0; i < 4; ++i) {
    const int c = i * 256 + tid;
    const int row = c >> 4, sgk = (c & 15) ^ (row & 7);
    kg[i] = KV + ((long)(b * 1024 + row)) * 1024 + kh * 256 + sgk * 8;
    const int d = c >> 3, sgv = (c & 7) ^ (d & 7);
    vg[i] = Vt + ((long)((b * 4 + kh) * 128 + d)) * 1024 + sgv * 8;
    ld[i] = c * 8;
  }

  float m_s = -__builtin_inff(), l_s = 0.f;
  const floatx4 fz = {0.f, 0.f, 0.f, 0.f};
  floatx4 yacc[8];
#pragma unroll
  for (int dt = 0; dt < 8; ++dt) yacc[dt] = fz;

  const int xk = (lr & 7) << 4;   // read-side XOR swizzle

  // prologue: stage K0 and V0 into buffer 0
#pragma unroll
  for (int i = 0; i < 4; ++i) async16(kg[i], &Kl[0][ld[i]]);
#pragma unroll
  for (int i = 0; i < 4; ++i) async16(vg[i], &Vl[0][ld[i]]);

  for (int t = 0; t <= qt; ++t) {
    const ushort_t* KlC = &Kl[t & 1][0];
    const ushort_t* VlC = &Vl[t & 1][0];
    if (t < qt) {           // prefetch K[t+1] into other K buffer
      const long ko = (long)(t + 1) * 65536;
      ushort_t* KlN = &Kl[(t + 1) & 1][0];
#pragma unroll
      for (int i = 0; i < 4; ++i) async16(kg[i] + ko, &KlN[ld[i]]);
      asm volatile("s_waitcnt vmcnt(8)" ::: "memory");   // this wave's K[t] retired
    } else {
      asm volatile("s_waitcnt vmcnt(4)" ::: "memory");
    }
    __builtin_amdgcn_s_barrier();   // barrier A: all waves' K[t] quarters in LDS
    cfence();

    // S^T = K * Q^T : lane holds q = lr, k = t*64 + k2*16 + lg*4 + r
    floatx4 st[4];
#pragma unroll
    for (int k2 = 0; k2 < 4; ++k2) {
      floatx4 s = fz;
      const int row = k2 * 16 + lr;
#pragma unroll
      for (int c = 0; c < 4; ++c) {
        const int off = row * 256 + ((c * 64 + lg * 16) ^ xk);
        const short8 kf = *(const short8*)((const char*)KlC + off);
        s = mfma16(kf, qf[c], s);
      }
      st[k2] = s;
    }
    if (t == qt) {  // causal mask on diagonal tile
      const int qg = qrow + lr;
#pragma unroll
      for (int k2 = 0; k2 < 4; ++k2)
#pragma unroll
        for (int r = 0; r < 4; ++r)
          if (t * 64 + k2 * 16 + lg * 4 + r > qg) st[k2][r] = -__builtin_inff();
    }
    // online softmax (stats at q = lr, replicated over lane-groups)
    float pm = -__builtin_inff();
#pragma unroll
    for (int k2 = 0; k2 < 4; ++k2)
      pm = fmaxf(pm, fmaxf(fmaxf(st[k2][0], st[k2][1]), fmaxf(st[k2][2], st[k2][3])));
    pm = fmaxf(pm, __shfl_xor(pm, 16));
    pm = fmaxf(pm, __shfl_xor(pm, 32));
    const float m_new = fmaxf(m_s, pm);
    const float corr = __expf(m_s - m_new);
    // P-fence: drain ALL of this wave's DS reads (incl. last tile's PV reads)
    asm volatile("s_waitcnt lgkmcnt(0)" ::: "memory");
    float psum = 0.f;
#pragma unroll
    for (int k2 = 0; k2 < 4; ++k2) {
      union { short4v v; ushort_t u[4]; } pk;
#pragma unroll
      for (int r = 0; r < 4; ++r) {
        const float pe = __expf(st[k2][r] - m_new);
        psum += pe;
        pk.u[r] = f2bf(pe);
      }
      *(short4v*)&Pl[w][lr][k2 * 16 + lg * 4] = pk.v;
    }
    psum += __shfl_xor(psum, 16);
    psum += __shfl_xor(psum, 32);
    l_s = l_s * corr + psum;
    m_s = m_new;
    const float cc0 = __shfl(corr, lg * 4 + 0);
    const float cc1 = __shfl(corr, lg * 4 + 1);
    const float cc2 = __shfl(corr, lg * 4 + 2);
    const float cc3 = __shfl(corr, lg * 4 + 3);
#pragma unroll
    for (int dt = 0; dt < 8; ++dt) {
      yacc[dt][0] *= cc0; yacc[dt][1] *= cc1;
      yacc[dt][2] *= cc2; yacc[dt][3] *= cc3;
    }
    // this wave's V[t] DMA retired (K[t+1] stays in flight) + P writes drained
    if (t < qt) asm volatile("s_waitcnt vmcnt(4)" ::: "memory");
    else        asm volatile("s_waitcnt vmcnt(0)" ::: "memory");
    asm volatile("s_waitcnt lgkmcnt(0)" ::: "memory");
    __builtin_amdgcn_s_barrier();   // barrier B: all waves' V[t] + P in LDS
    cfence();

    // PV: y[q][d] += P[q][k] V[k][d]
#pragma unroll
    for (int kc = 0; kc < 2; ++kc) {
      const short8 pf = *(const short8*)&Pl[w][lr][kc * 32 + lg * 8];
#pragma unroll
      for (int dt = 0; dt < 8; ++dt) {
        const int d = dt * 16 + lr;
        const int off = d * 128 + ((kc * 64 + lg * 16) ^ xk);
        const short8 vf = *(const short8*)((const char*)VlC + off);
        yacc[dt] = mfma16(pf, vf, yacc[dt]);
      }
    }
    cfence();
    if (t < qt) {   // stage V[t+1] into other V buffer; hides under next QK+softmax
      const long vo = (long)(t + 1) * 64;
      ushort_t* VlN = &Vl[(t + 1) & 1][0];
#pragma unroll
      for (int i = 0; i < 4; ++i) async16(vg[i] + vo, &VlN[ld[i]]);
    }
  }

  const float linv = 1.f / l_s;
  const float i0 = __shfl(linv, lg * 4 + 0);
  const float i1 = __shfl(linv, lg * 4 + 1);
  const float i2 = __shfl(linv, lg * 4 + 2);
  const float i3 = __shfl(linv, lg * 4 + 3);
  ushort_t* yp = Y + ((long)(b * 1024 + qrow)) * 2048 + h * 128 + lr;
#pragma unroll
  for (int dt = 0; dt < 8; ++dt) {
    yp[(long)(lg * 4 + 0) * 2048 + dt * 16] = f2bf(yacc[dt][0] * i0);
    yp[(long)(lg * 4 + 1) * 2048 + dt * 16] = f2bf(yacc[dt][1] * i1);
    yp[(long)(lg * 4 + 2) * 2048 + dt * 16] = f2bf(yacc[dt][2] * i2);
    yp[(long)(lg * 4 + 3) * 2048 + dt * 16] = f2bf(yacc[dt][3] * i3);
  }
}

// ---------------- launch ----------------
extern "C" void kernel_launch(void* const* d_in, const int* in_sizes, int n_in,
                              void* d_out, int out_size, void* d_ws, size_t ws_size,
                              hipStream_t stream)
{
  (void)in_sizes; (void)n_in; (void)out_size;
  const float* x   = (const float*)d_in[0];
  const float* Wq  = (const float*)d_in[1];
  const float* bq  = (const float*)d_in[2];
  const float* Wkv = (const float*)d_in[3];
  const float* bkv = (const float*)d_in[4];
  const float* Wo  = (const float*)d_in[5];
  const float* bo  = (const float*)d_in[6];
  float* out = (float*)d_out;
  char* ws = (char*)d_ws;

  if (ws_size < 104857600) return;  // need 100 MB

  const long NX = 8192L * 2048, NWQ = 2048L * 2048, NWKV = 1024L * 2048, NWO = 2048L * 2048;
  ushort_t* xb   = (ushort_t*)(ws);              // 32MB; reused as Y after KV GEMM
  ushort_t* Qb   = (ushort_t*)(ws + 33554432);   // 32MB
  ushort_t* KVb  = (ushort_t*)(ws + 67108864);   // 16MB
  ushort_t* Wqb  = (ushort_t*)(ws + 83886080);   // 8MB; reused as Vt after Q GEMM
  ushort_t* Wkvb = (ushort_t*)(ws + 92274688);   // 4MB
  ushort_t* Wob  = (ushort_t*)(ws + 96468992);   // 8MB
  ushort_t* Vtb  = Wqb;
  ushort_t* Yb   = xb;

  k_f2bf<<<dim3(NX   / 2048), 256, 0, stream>>>(x,   xb,   NX);
  k_f2bf<<<dim3(NWQ  / 2048), 256, 0, stream>>>(Wq,  Wqb,  NWQ);
  k_f2bf<<<dim3(NWKV / 2048), 256, 0, stream>>>(Wkv, Wkvb, NWKV);
  k_f2bf<<<dim3(NWO  / 2048), 256, 0, stream>>>(Wo,  Wob,  NWO);

  const float scale = 0.08838834764831845f;  // 1/sqrt(128), folded into Q
  k_gemm<1><<<dim3(16, 64), 256, 0, stream>>>(xb, Wqb,  bq,  Qb,  2048, 2048, scale);
  k_gemm<1><<<dim3(8,  64), 256, 0, stream>>>(xb, Wkvb, bkv, KVb, 1024, 2048, 1.0f);
  k_transv<<<dim3(16, 4, 8), 256, 0, stream>>>(KVb, Vtb);
  k_attn<<<dim3(2048), 256, 0, stream>>>(Qb, KVb, Vtb, Yb);
  k_gemm<0><<<dim3(16, 64), 256, 0, stream>>>(Yb, Wob, bo, out, 2048, 2048, 1.0f);
}

// Round 5
// 392.822 us; speedup vs baseline: 1.9314x; 1.0510x over previous
//
#include <hip/hip_runtime.h>

typedef short short8 __attribute__((ext_vector_type(8)));
typedef short short4v __attribute__((ext_vector_type(4)));
typedef float floatx4 __attribute__((ext_vector_type(4)));
typedef unsigned short ushort_t;
typedef unsigned int uint_t;

#define DI __device__ __forceinline__

DI ushort_t f2bf(float f) {
  uint_t u = __builtin_bit_cast(uint_t, f);
  uint_t r = u + 0x7FFFu + ((u >> 16) & 1u);
  return (ushort_t)(r >> 16);
}

DI floatx4 mfma16(short8 a, short8 b, floatx4 c) {
  return __builtin_amdgcn_mfma_f32_16x16x32_bf16(a, b, c, 0, 0, 0);
}

DI void async16(const void* g, void* l) {
  __builtin_amdgcn_global_load_lds(
      (__attribute__((address_space(1))) void*)(g),
      (__attribute__((address_space(3))) void*)(l), 16, 0, 0);
}

// compiler memory fence (zero instructions) — pins memory ops across raw s_barrier
DI void cfence() { asm volatile("" ::: "memory"); }

// ---------------- f32 -> bf16 conversion, 8 elems/thread ----------------
__global__ __launch_bounds__(256)
void k_f2bf(const float* __restrict__ in, ushort_t* __restrict__ out, long n)
{
  const long i = ((long)blockIdx.x * 256 + threadIdx.x) * 8;
  if (i >= n) return;
  const float4 a = *(const float4*)(in + i);
  const float4 b = *(const float4*)(in + i + 4);
  union { short8 s; ushort_t u[8]; } o;
  o.u[0] = f2bf(a.x); o.u[1] = f2bf(a.y); o.u[2] = f2bf(a.z); o.u[3] = f2bf(a.w);
  o.u[4] = f2bf(b.x); o.u[5] = f2bf(b.y); o.u[6] = f2bf(b.z); o.u[7] = f2bf(b.w);
  *(short8*)(out + i) = o.s;
}

// ---------------- GEMM: C[M,N] = A[M,K] * B[N,K]^T, bf16 in, 128x128 tile ----------------
// Double-buffered LDS, prefetch-ahead with counted vmcnt (never 0 mid-loop).
// Race invariant (proven pattern from k_attn): each wave drains its DS reads
// (lgkmcnt(0)) before barrier B; any DMA overwriting a buffer is issued after a
// later barrier B. Data-ready: vmcnt(4) retires tile t's granules before barrier A.
template<int OUT_BF16>
__global__ __launch_bounds__(256)
void k_gemm(const ushort_t* __restrict__ A, const ushort_t* __restrict__ B,
            const float* __restrict__ bias, void* __restrict__ Cout,
            int N, int K, float out_scale)
{
  __shared__ __align__(16) ushort_t As[2][128 * 32];
  __shared__ __align__(16) ushort_t Bs[2][128 * 32];
  const int tid = threadIdx.x;
  const int w = tid >> 6, l = tid & 63;
  const int wm = w >> 1, wn = w & 1;      // 2x2 waves, each 64x64 output
  const int lr = l & 15, lg = l >> 4;
  const long m0 = (long)blockIdx.y * 128;
  const long n0 = (long)blockIdx.x * 128;

  const floatx4 fz = {0.f, 0.f, 0.f, 0.f};
  floatx4 acc[4][4];
#pragma unroll
  for (int i = 0; i < 4; ++i)
#pragma unroll
    for (int j = 0; j < 4; ++j) acc[i][j] = fz;

  // staging: chunk c in [0,512): row=c>>2, col=(c&3)*8 ; LDS dest byte = c*16
  const int c0 = tid, c1 = 256 + tid;
  const ushort_t* gA0 = A + (m0 + (c0 >> 2)) * K + ((c0 & 3) << 3);
  const ushort_t* gA1 = A + (m0 + (c1 >> 2)) * K + ((c1 & 3) << 3);
  const ushort_t* gB0 = B + (n0 + (c0 >> 2)) * K + ((c0 & 3) << 3);
  const ushort_t* gB1 = B + (n0 + (c1 >> 2)) * K + ((c1 & 3) << 3);

  const int nK = K >> 5;
  // prologue: stage tile 0 into buffer 0
  async16(gA0, &As[0][c0 * 8]);
  async16(gA1, &As[0][c1 * 8]);
  async16(gB0, &Bs[0][c0 * 8]);
  async16(gB1, &Bs[0][c1 * 8]);

  for (int kt = 0; kt < nK; ++kt) {
    const int cur = kt & 1;
    if (kt + 1 < nK) {            // prefetch tile kt+1 into other buffer
      const int ko = (kt + 1) << 5;
      async16(gA0 + ko, &As[cur ^ 1][c0 * 8]);
      async16(gA1 + ko, &As[cur ^ 1][c1 * 8]);
      async16(gB0 + ko, &Bs[cur ^ 1][c0 * 8]);
      async16(gB1 + ko, &Bs[cur ^ 1][c1 * 8]);
      asm volatile("s_waitcnt vmcnt(4)" ::: "memory");  // tile kt's granules retired
    } else {
      asm volatile("s_waitcnt vmcnt(0)" ::: "memory");
    }
    __builtin_amdgcn_s_barrier();   // barrier A: tile kt fully in LDS
    cfence();

    short8 a[4], b[4];
#pragma unroll
    for (int i = 0; i < 4; ++i)
      a[i] = *(const short8*)&As[cur][(wm * 64 + i * 16 + lr) * 32 + lg * 8];
#pragma unroll
    for (int j = 0; j < 4; ++j)
      b[j] = *(const short8*)&Bs[cur][(wn * 64 + j * 16 + lr) * 32 + lg * 8];
#pragma unroll
    for (int i = 0; i < 4; ++i)
#pragma unroll
      for (int j = 0; j < 4; ++j)
        acc[i][j] = mfma16(a[i], b[j], acc[i][j]);

    asm volatile("s_waitcnt lgkmcnt(0)" ::: "memory");  // this wave's ds_reads done
    __builtin_amdgcn_s_barrier();   // barrier B: all waves done reading buf cur
    cfence();                        // next iter's DMA into cur stays below
  }

#pragma unroll
  for (int j = 0; j < 4; ++j) {
    const long gn = n0 + wn * 64 + j * 16 + lr;
    const float bv = bias[gn];
#pragma unroll
    for (int i = 0; i < 4; ++i) {
      const long gm = m0 + wm * 64 + i * 16 + lg * 4;
#pragma unroll
      for (int r = 0; r < 4; ++r) {
        const float v = (acc[i][j][r] + bv) * out_scale;
        if (OUT_BF16) ((ushort_t*)Cout)[(gm + r) * N + gn] = f2bf(v);
        else          ((float*)Cout)[(gm + r) * N + gn] = v;
      }
    }
  }
}

// ---------------- V transpose: KV[b,t,kh,{k,v},d] -> Vt[b,kh,d,t] ----------------
__global__ __launch_bounds__(256)
void k_transv(const ushort_t* __restrict__ KV, ushort_t* __restrict__ Vt)
{
  const int tblk = blockIdx.x, kh = blockIdx.y, b = blockIdx.z;
  const int tid = threadIdx.x;
#pragma unroll
  for (int j = 0; j < 4; ++j) {
    const int c = j * 256 + tid;
    const int d = c >> 3, t0 = (c & 7) << 3;
    const ushort_t* src = KV + (long)(b * 1024 + tblk * 64 + t0) * 1024 + kh * 256 + 128 + d;
    union { short8 s; ushort_t u[8]; } vv;
#pragma unroll
    for (int i = 0; i < 8; ++i) vv.u[i] = src[(long)i * 1024];
    *(short8*)(Vt + ((long)(b * 4 + kh) * 128 + d) * 1024 + tblk * 64 + t0) = vv.s;
  }
}

// ---------------- Flash attention (causal, GQA), LDS-staged + counted vmcnt ----------------
// (unchanged from round 4 — passed deterministic)
__global__ __launch_bounds__(256)
void k_attn(const ushort_t* __restrict__ Q, const ushort_t* __restrict__ KV,
            const ushort_t* __restrict__ Vt, ushort_t* __restrict__ Y)
{
  __shared__ __align__(16) ushort_t Kl[2][64 * 128];   // 32 KB
  __shared__ __align__(16) ushort_t Vl[2][128 * 64];   // 32 KB
  __shared__ __align__(16) ushort_t Pl[4][16][72];     // 9.2 KB
  const int tid = threadIdx.x;
  const int w = tid >> 6, l = tid & 63;
  const int lr = l & 15, lg = l >> 4;
  // remap: batch b pinned per XCD (K+V 2MB fits 4MB L2); long diagonals first
  const int p = blockIdx.x;
  const int v = ((p & 7) << 8) | (p >> 3);
  const int b = v >> 8;
  const int kh = (v >> 6) & 3;
  const int hs = (v >> 4) & 3;
  const int qt = 15 - (v & 15);
  const int h = kh * 4 + hs;
  const int qrow = qt * 64 + w * 16;

  const ushort_t* qptr = Q + ((long)(b * 1024 + qrow + lr)) * 2048 + h * 128 + lg * 8;
  short8 qf[4];
#pragma unroll
  for (int c = 0; c < 4; ++c) qf[c] = *(const short8*)(qptr + c * 32);

  // staging source pointers (pre-swizzled granules) + linear LDS offsets
  const ushort_t* kg[4];
  const ushort_t* vg[4];
  int ld[4];
#pragma unroll
  for (int i = 0; i < 4; ++i) {
    const int c = i * 256 + tid;
    const int row = c >> 4, sgk = (c & 15) ^ (row & 7);
    kg[i] = KV + ((long)(b * 1024 + row)) * 1024 + kh * 256 + sgk * 8;
    const int d = c >> 3, sgv = (c & 7) ^ (d & 7);
    vg[i] = Vt + ((long)((b * 4 + kh) * 128 + d)) * 1024 + sgv * 8;
    ld[i] = c * 8;
  }

  float m_s = -__builtin_inff(), l_s = 0.f;
  const floatx4 fz = {0.f, 0.f, 0.f, 0.f};
  floatx4 yacc[8];
#pragma unroll
  for (int dt = 0; dt < 8; ++dt) yacc[dt] = fz;

  const int xk = (lr & 7) << 4;   // read-side XOR swizzle

  // prologue: stage K0 and V0 into buffer 0
#pragma unroll
  for (int i = 0; i < 4; ++i) async16(kg[i], &Kl[0][ld[i]]);
#pragma unroll
  for (int i = 0; i < 4; ++i) async16(vg[i], &Vl[0][ld[i]]);

  for (int t = 0; t <= qt; ++t) {
    const ushort_t* KlC = &Kl[t & 1][0];
    const ushort_t* VlC = &Vl[t & 1][0];
    if (t < qt) {           // prefetch K[t+1] into other K buffer
      const long ko = (long)(t + 1) * 65536;
      ushort_t* KlN = &Kl[(t + 1) & 1][0];
#pragma unroll
      for (int i = 0; i < 4; ++i) async16(kg[i] + ko, &KlN[ld[i]]);
      asm volatile("s_waitcnt vmcnt(8)" ::: "memory");   // this wave's K[t] retired
    } else {
      asm volatile("s_waitcnt vmcnt(4)" ::: "memory");
    }
    __builtin_amdgcn_s_barrier();   // barrier A: all waves' K[t] quarters in LDS
    cfence();

    // S^T = K * Q^T : lane holds q = lr, k = t*64 + k2*16 + lg*4 + r
    floatx4 st[4];
#pragma unroll
    for (int k2 = 0; k2 < 4; ++k2) {
      floatx4 s = fz;
      const int row = k2 * 16 + lr;
#pragma unroll
      for (int c = 0; c < 4; ++c) {
        const int off = row * 256 + ((c * 64 + lg * 16) ^ xk);
        const short8 kf = *(const short8*)((const char*)KlC + off);
        s = mfma16(kf, qf[c], s);
      }
      st[k2] = s;
    }
    if (t == qt) {  // causal mask on diagonal tile
      const int qg = qrow + lr;
#pragma unroll
      for (int k2 = 0; k2 < 4; ++k2)
#pragma unroll
        for (int r = 0; r < 4; ++r)
          if (t * 64 + k2 * 16 + lg * 4 + r > qg) st[k2][r] = -__builtin_inff();
    }
    // online softmax (stats at q = lr, replicated over lane-groups)
    float pm = -__builtin_inff();
#pragma unroll
    for (int k2 = 0; k2 < 4; ++k2)
      pm = fmaxf(pm, fmaxf(fmaxf(st[k2][0], st[k2][1]), fmaxf(st[k2][2], st[k2][3])));
    pm = fmaxf(pm, __shfl_xor(pm, 16));
    pm = fmaxf(pm, __shfl_xor(pm, 32));
    const float m_new = fmaxf(m_s, pm);
    const float corr = __expf(m_s - m_new);
    // P-fence: drain ALL of this wave's DS reads (incl. last tile's PV reads)
    asm volatile("s_waitcnt lgkmcnt(0)" ::: "memory");
    float psum = 0.f;
#pragma unroll
    for (int k2 = 0; k2 < 4; ++k2) {
      union { short4v v; ushort_t u[4]; } pk;
#pragma unroll
      for (int r = 0; r < 4; ++r) {
        const float pe = __expf(st[k2][r] - m_new);
        psum += pe;
        pk.u[r] = f2bf(pe);
      }
      *(short4v*)&Pl[w][lr][k2 * 16 + lg * 4] = pk.v;
    }
    psum += __shfl_xor(psum, 16);
    psum += __shfl_xor(psum, 32);
    l_s = l_s * corr + psum;
    m_s = m_new;
    const float cc0 = __shfl(corr, lg * 4 + 0);
    const float cc1 = __shfl(corr, lg * 4 + 1);
    const float cc2 = __shfl(corr, lg * 4 + 2);
    const float cc3 = __shfl(corr, lg * 4 + 3);
#pragma unroll
    for (int dt = 0; dt < 8; ++dt) {
      yacc[dt][0] *= cc0; yacc[dt][1] *= cc1;
      yacc[dt][2] *= cc2; yacc[dt][3] *= cc3;
    }
    // this wave's V[t] DMA retired (K[t+1] stays in flight) + P writes drained
    if (t < qt) asm volatile("s_waitcnt vmcnt(4)" ::: "memory");
    else        asm volatile("s_waitcnt vmcnt(0)" ::: "memory");
    asm volatile("s_waitcnt lgkmcnt(0)" ::: "memory");
    __builtin_amdgcn_s_barrier();   // barrier B: all waves' V[t] + P in LDS
    cfence();

    // PV: y[q][d] += P[q][k] V[k][d]
#pragma unroll
    for (int kc = 0; kc < 2; ++kc) {
      const short8 pf = *(const short8*)&Pl[w][lr][kc * 32 + lg * 8];
#pragma unroll
      for (int dt = 0; dt < 8; ++dt) {
        const int d = dt * 16 + lr;
        const int off = d * 128 + ((kc * 64 + lg * 16) ^ xk);
        const short8 vf = *(const short8*)((const char*)VlC + off);
        yacc[dt] = mfma16(pf, vf, yacc[dt]);
      }
    }
    cfence();
    if (t < qt) {   // stage V[t+1] into other V buffer; hides under next QK+softmax
      const long vo = (long)(t + 1) * 64;
      ushort_t* VlN = &Vl[(t + 1) & 1][0];
#pragma unroll
      for (int i = 0; i < 4; ++i) async16(vg[i] + vo, &VlN[ld[i]]);
    }
  }

  const float linv = 1.f / l_s;
  const float i0 = __shfl(linv, lg * 4 + 0);
  const float i1 = __shfl(linv, lg * 4 + 1);
  const float i2 = __shfl(linv, lg * 4 + 2);
  const float i3 = __shfl(linv, lg * 4 + 3);
  ushort_t* yp = Y + ((long)(b * 1024 + qrow)) * 2048 + h * 128 + lr;
#pragma unroll
  for (int dt = 0; dt < 8; ++dt) {
    yp[(long)(lg * 4 + 0) * 2048 + dt * 16] = f2bf(yacc[dt][0] * i0);
    yp[(long)(lg * 4 + 1) * 2048 + dt * 16] = f2bf(yacc[dt][1] * i1);
    yp[(long)(lg * 4 + 2) * 2048 + dt * 16] = f2bf(yacc[dt][2] * i2);
    yp[(long)(lg * 4 + 3) * 2048 + dt * 16] = f2bf(yacc[dt][3] * i3);
  }
}

// ---------------- launch ----------------
extern "C" void kernel_launch(void* const* d_in, const int* in_sizes, int n_in,
                              void* d_out, int out_size, void* d_ws, size_t ws_size,
                              hipStream_t stream)
{
  (void)in_sizes; (void)n_in; (void)out_size;
  const float* x   = (const float*)d_in[0];
  const float* Wq  = (const float*)d_in[1];
  const float* bq  = (const float*)d_in[2];
  const float* Wkv = (const float*)d_in[3];
  const float* bkv = (const float*)d_in[4];
  const float* Wo  = (const float*)d_in[5];
  const float* bo  = (const float*)d_in[6];
  float* out = (float*)d_out;
  char* ws = (char*)d_ws;

  if (ws_size < 104857600) return;  // need 100 MB

  const long NX = 8192L * 2048, NWQ = 2048L * 2048, NWKV = 1024L * 2048, NWO = 2048L * 2048;
  ushort_t* xb   = (ushort_t*)(ws);              // 32MB; reused as Y after KV GEMM
  ushort_t* Qb   = (ushort_t*)(ws + 33554432);   // 32MB
  ushort_t* KVb  = (ushort_t*)(ws + 67108864);   // 16MB
  ushort_t* Wqb  = (ushort_t*)(ws + 83886080);   // 8MB; reused as Vt after Q GEMM
  ushort_t* Wkvb = (ushort_t*)(ws + 92274688);   // 4MB
  ushort_t* Wob  = (ushort_t*)(ws + 96468992);   // 8MB
  ushort_t* Vtb  = Wqb;
  ushort_t* Yb   = xb;

  k_f2bf<<<dim3(NX   / 2048), 256, 0, stream>>>(x,   xb,   NX);
  k_f2bf<<<dim3(NWQ  / 2048), 256, 0, stream>>>(Wq,  Wqb,  NWQ);
  k_f2bf<<<dim3(NWKV / 2048), 256, 0, stream>>>(Wkv, Wkvb, NWKV);
  k_f2bf<<<dim3(NWO  / 2048), 256, 0, stream>>>(Wo,  Wob,  NWO);

  const float scale = 0.08838834764831845f;  // 1/sqrt(128), folded into Q
  k_gemm<1><<<dim3(16, 64), 256, 0, stream>>>(xb, Wqb,  bq,  Qb,  2048, 2048, scale);
  k_gemm<1><<<dim3(8,  64), 256, 0, stream>>>(xb, Wkvb, bkv, KVb, 1024, 2048, 1.0f);
  k_transv<<<dim3(16, 4, 8), 256, 0, stream>>>(KVb, Vtb);
  k_attn<<<dim3(2048), 256, 0, stream>>>(Qb, KVb, Vtb, Yb);
  k_gemm<0><<<dim3(16, 64), 256, 0, stream>>>(Yb, Wob, bo, out, 2048, 2048, 1.0f);
}

// Round 6
// 384.796 us; speedup vs baseline: 1.9717x; 1.0209x over previous
//
#include <hip/hip_runtime.h>

typedef short short8 __attribute__((ext_vector_type(8)));
typedef short short4v __attribute__((ext_vector_type(4)));
typedef float floatx4 __attribute__((ext_vector_type(4)));
typedef unsigned short ushort_t;
typedef unsigned int uint_t;

#define DI __device__ __forceinline__

DI ushort_t f2bf(float f) {
  uint_t u = __builtin_bit_cast(uint_t, f);
  uint_t r = u + 0x7FFFu + ((u >> 16) & 1u);
  return (ushort_t)(r >> 16);
}

DI floatx4 mfma16(short8 a, short8 b, floatx4 c) {
  return __builtin_amdgcn_mfma_f32_16x16x32_bf16(a, b, c, 0, 0, 0);
}

DI void async16(const void* g, void* l) {
  __builtin_amdgcn_global_load_lds(
      (__attribute__((address_space(1))) void*)(g),
      (__attribute__((address_space(3))) void*)(l), 16, 0, 0);
}

// compiler memory fence (zero instructions) — pins memory ops across raw s_barrier
DI void cfence() { asm volatile("" ::: "memory"); }

// ---------------- f32 -> bf16 conversion, 8 elems/thread ----------------
__global__ __launch_bounds__(256)
void k_f2bf(const float* __restrict__ in, ushort_t* __restrict__ out, long n)
{
  const long i = ((long)blockIdx.x * 256 + threadIdx.x) * 8;
  if (i >= n) return;
  const float4 a = *(const float4*)(in + i);
  const float4 b = *(const float4*)(in + i + 4);
  union { short8 s; ushort_t u[8]; } o;
  o.u[0] = f2bf(a.x); o.u[1] = f2bf(a.y); o.u[2] = f2bf(a.z); o.u[3] = f2bf(a.w);
  o.u[4] = f2bf(b.x); o.u[5] = f2bf(b.y); o.u[6] = f2bf(b.z); o.u[7] = f2bf(b.w);
  *(short8*)(out + i) = o.s;
}

// ---------------- GEMM: C[M,N] = A[M,K] * B[N,K]^T, bf16 in, 128x128 tile ----------------
// Quad-buffered LDS, prefetch depth 3 (tile t+3 issued at step t), counted vmcnt(12).
// LDS granule swizzle: within each row's 4x16B granules, slot s holds source granule
// s ^ (row&3) (pre-swizzled SOURCE + swizzled READ — both-sides involution, m173).
// Race invariant: buf[(t+3)&3] last read at step t-1; every wave drains its ds_reads
// (lgkmcnt(0)) before barrier B(t-1); the overwriting DMA is issued after that barrier.
template<int OUT_BF16>
__global__ __launch_bounds__(256)
void k_gemm(const ushort_t* __restrict__ A, const ushort_t* __restrict__ B,
            const float* __restrict__ bias, void* __restrict__ Cout,
            int N, int K, float out_scale)
{
  __shared__ __align__(16) ushort_t As[4][128 * 32];
  __shared__ __align__(16) ushort_t Bs[4][128 * 32];
  const int tid = threadIdx.x;
  const int w = tid >> 6, l = tid & 63;
  const int wm = w >> 1, wn = w & 1;      // 2x2 waves, each 64x64 output
  const int lr = l & 15, lg = l >> 4;
  const long m0 = (long)blockIdx.y * 128;
  const long n0 = (long)blockIdx.x * 128;

  const floatx4 fz = {0.f, 0.f, 0.f, 0.f};
  floatx4 acc[4][4];
#pragma unroll
  for (int i = 0; i < 4; ++i)
#pragma unroll
    for (int j = 0; j < 4; ++j) acc[i][j] = fz;

  // staging chunk c in [0,512): row=c>>2, dest slot=c&3, LDS dest byte = c*16.
  // source granule = slot ^ (row&3)  (pre-swizzle so LDS[row][s] = src[row][s^(row&3)])
  const int c0 = tid, c1 = 256 + tid;
  const int r0 = c0 >> 2, r1 = c1 >> 2;
  const ushort_t* gA0 = A + (m0 + r0) * K + (((c0 & 3) ^ (r0 & 3)) << 3);
  const ushort_t* gA1 = A + (m0 + r1) * K + (((c1 & 3) ^ (r1 & 3)) << 3);
  const ushort_t* gB0 = B + (n0 + r0) * K + (((c0 & 3) ^ (r0 & 3)) << 3);
  const ushort_t* gB1 = B + (n0 + r1) * K + (((c1 & 3) ^ (r1 & 3)) << 3);

  const int nK = K >> 5;
  // prologue: stage tiles 0,1,2 into buffers 0,1,2
#pragma unroll
  for (int pt = 0; pt < 3; ++pt) {
    const int ko = pt << 5;
    async16(gA0 + ko, &As[pt][c0 * 8]);
    async16(gA1 + ko, &As[pt][c1 * 8]);
    async16(gB0 + ko, &Bs[pt][c0 * 8]);
    async16(gB1 + ko, &Bs[pt][c1 * 8]);
  }

  const int xg = (lr & 3);   // read-side granule XOR (row = ...16*i + lr, row&3 = lr&3)

  for (int kt = 0; kt < nK; ++kt) {
    const int cur = kt & 3;
    const int rem = nK - 1 - kt;
    if (rem >= 3) {               // prefetch tile kt+3 into buf (kt+3)&3
      const int ko = (kt + 3) << 5;
      const int nb = (kt + 3) & 3;
      async16(gA0 + ko, &As[nb][c0 * 8]);
      async16(gA1 + ko, &As[nb][c1 * 8]);
      async16(gB0 + ko, &Bs[nb][c0 * 8]);
      async16(gB1 + ko, &Bs[nb][c1 * 8]);
      asm volatile("s_waitcnt vmcnt(12)" ::: "memory");  // tile kt retired; 3 in flight
    } else if (rem == 2) {
      asm volatile("s_waitcnt vmcnt(8)" ::: "memory");
    } else if (rem == 1) {
      asm volatile("s_waitcnt vmcnt(4)" ::: "memory");
    } else {
      asm volatile("s_waitcnt vmcnt(0)" ::: "memory");
    }
    __builtin_amdgcn_s_barrier();   // barrier A: tile kt fully in LDS
    cfence();

    short8 a[4], b[4];
#pragma unroll
    for (int i = 0; i < 4; ++i)
      a[i] = *(const short8*)&As[cur][(wm * 64 + i * 16 + lr) * 32 + ((lg ^ xg) * 8)];
#pragma unroll
    for (int j = 0; j < 4; ++j)
      b[j] = *(const short8*)&Bs[cur][(wn * 64 + j * 16 + lr) * 32 + ((lg ^ xg) * 8)];
#pragma unroll
    for (int i = 0; i < 4; ++i)
#pragma unroll
      for (int j = 0; j < 4; ++j)
        acc[i][j] = mfma16(a[i], b[j], acc[i][j]);

    asm volatile("s_waitcnt lgkmcnt(0)" ::: "memory");  // this wave's ds_reads done
    __builtin_amdgcn_s_barrier();   // barrier B: all waves done reading buf cur
    cfence();                        // later DMA into cur stays below
  }

#pragma unroll
  for (int j = 0; j < 4; ++j) {
    const long gn = n0 + wn * 64 + j * 16 + lr;
    const float bv = bias[gn];
#pragma unroll
    for (int i = 0; i < 4; ++i) {
      const long gm = m0 + wm * 64 + i * 16 + lg * 4;
#pragma unroll
      for (int r = 0; r < 4; ++r) {
        const float v = (acc[i][j][r] + bv) * out_scale;
        if (OUT_BF16) ((ushort_t*)Cout)[(gm + r) * N + gn] = f2bf(v);
        else          ((float*)Cout)[(gm + r) * N + gn] = v;
      }
    }
  }
}

// ---------------- V transpose: KV[b,t,kh,{k,v},d] -> Vt[b,kh,d,t] ----------------
__global__ __launch_bounds__(256)
void k_transv(const ushort_t* __restrict__ KV, ushort_t* __restrict__ Vt)
{
  const int tblk = blockIdx.x, kh = blockIdx.y, b = blockIdx.z;
  const int tid = threadIdx.x;
#pragma unroll
  for (int j = 0; j < 4; ++j) {
    const int c = j * 256 + tid;
    const int d = c >> 3, t0 = (c & 7) << 3;
    const ushort_t* src = KV + (long)(b * 1024 + tblk * 64 + t0) * 1024 + kh * 256 + 128 + d;
    union { short8 s; ushort_t u[8]; } vv;
#pragma unroll
    for (int i = 0; i < 8; ++i) vv.u[i] = src[(long)i * 1024];
    *(short8*)(Vt + ((long)(b * 4 + kh) * 128 + d) * 1024 + tblk * 64 + t0) = vv.s;
  }
}

// ---------------- Flash attention (causal, GQA), LDS-staged + counted vmcnt ----------------
// (unchanged from round 4/5 — passed deterministic)
__global__ __launch_bounds__(256)
void k_attn(const ushort_t* __restrict__ Q, const ushort_t* __restrict__ KV,
            const ushort_t* __restrict__ Vt, ushort_t* __restrict__ Y)
{
  __shared__ __align__(16) ushort_t Kl[2][64 * 128];   // 32 KB
  __shared__ __align__(16) ushort_t Vl[2][128 * 64];   // 32 KB
  __shared__ __align__(16) ushort_t Pl[4][16][72];     // 9.2 KB
  const int tid = threadIdx.x;
  const int w = tid >> 6, l = tid & 63;
  const int lr = l & 15, lg = l >> 4;
  // remap: batch b pinned per XCD (K+V 2MB fits 4MB L2); long diagonals first
  const int p = blockIdx.x;
  const int v = ((p & 7) << 8) | (p >> 3);
  const int b = v >> 8;
  const int kh = (v >> 6) & 3;
  const int hs = (v >> 4) & 3;
  const int qt = 15 - (v & 15);
  const int h = kh * 4 + hs;
  const int qrow = qt * 64 + w * 16;

  const ushort_t* qptr = Q + ((long)(b * 1024 + qrow + lr)) * 2048 + h * 128 + lg * 8;
  short8 qf[4];
#pragma unroll
  for (int c = 0; c < 4; ++c) qf[c] = *(const short8*)(qptr + c * 32);

  // staging source pointers (pre-swizzled granules) + linear LDS offsets
  const ushort_t* kg[4];
  const ushort_t* vg[4];
  int ld[4];
#pragma unroll
  for (int i = 0; i < 4; ++i) {
    const int c = i * 256 + tid;
    const int row = c >> 4, sgk = (c & 15) ^ (row & 7);
    kg[i] = KV + ((long)(b * 1024 + row)) * 1024 + kh * 256 + sgk * 8;
    const int d = c >> 3, sgv = (c & 7) ^ (d & 7);
    vg[i] = Vt + ((long)((b * 4 + kh) * 128 + d)) * 1024 + sgv * 8;
    ld[i] = c * 8;
  }

  float m_s = -__builtin_inff(), l_s = 0.f;
  const floatx4 fz = {0.f, 0.f, 0.f, 0.f};
  floatx4 yacc[8];
#pragma unroll
  for (int dt = 0; dt < 8; ++dt) yacc[dt] = fz;

  const int xk = (lr & 7) << 4;   // read-side XOR swizzle

  // prologue: stage K0 and V0 into buffer 0
#pragma unroll
  for (int i = 0; i < 4; ++i) async16(kg[i], &Kl[0][ld[i]]);
#pragma unroll
  for (int i = 0; i < 4; ++i) async16(vg[i], &Vl[0][ld[i]]);

  for (int t = 0; t <= qt; ++t) {
    const ushort_t* KlC = &Kl[t & 1][0];
    const ushort_t* VlC = &Vl[t & 1][0];
    if (t < qt) {           // prefetch K[t+1] into other K buffer
      const long ko = (long)(t + 1) * 65536;
      ushort_t* KlN = &Kl[(t + 1) & 1][0];
#pragma unroll
      for (int i = 0; i < 4; ++i) async16(kg[i] + ko, &KlN[ld[i]]);
      asm volatile("s_waitcnt vmcnt(8)" ::: "memory");   // this wave's K[t] retired
    } else {
      asm volatile("s_waitcnt vmcnt(4)" ::: "memory");
    }
    __builtin_amdgcn_s_barrier();   // barrier A: all waves' K[t] quarters in LDS
    cfence();

    // S^T = K * Q^T : lane holds q = lr, k = t*64 + k2*16 + lg*4 + r
    floatx4 st[4];
#pragma unroll
    for (int k2 = 0; k2 < 4; ++k2) {
      floatx4 s = fz;
      const int row = k2 * 16 + lr;
#pragma unroll
      for (int c = 0; c < 4; ++c) {
        const int off = row * 256 + ((c * 64 + lg * 16) ^ xk);
        const short8 kf = *(const short8*)((const char*)KlC + off);
        s = mfma16(kf, qf[c], s);
      }
      st[k2] = s;
    }
    if (t == qt) {  // causal mask on diagonal tile
      const int qg = qrow + lr;
#pragma unroll
      for (int k2 = 0; k2 < 4; ++k2)
#pragma unroll
        for (int r = 0; r < 4; ++r)
          if (t * 64 + k2 * 16 + lg * 4 + r > qg) st[k2][r] = -__builtin_inff();
    }
    // online softmax (stats at q = lr, replicated over lane-groups)
    float pm = -__builtin_inff();
#pragma unroll
    for (int k2 = 0; k2 < 4; ++k2)
      pm = fmaxf(pm, fmaxf(fmaxf(st[k2][0], st[k2][1]), fmaxf(st[k2][2], st[k2][3])));
    pm = fmaxf(pm, __shfl_xor(pm, 16));
    pm = fmaxf(pm, __shfl_xor(pm, 32));
    const float m_new = fmaxf(m_s, pm);
    const float corr = __expf(m_s - m_new);
    // P-fence: drain ALL of this wave's DS reads (incl. last tile's PV reads)
    asm volatile("s_waitcnt lgkmcnt(0)" ::: "memory");
    float psum = 0.f;
#pragma unroll
    for (int k2 = 0; k2 < 4; ++k2) {
      union { short4v v; ushort_t u[4]; } pk;
#pragma unroll
      for (int r = 0; r < 4; ++r) {
        const float pe = __expf(st[k2][r] - m_new);
        psum += pe;
        pk.u[r] = f2bf(pe);
      }
      *(short4v*)&Pl[w][lr][k2 * 16 + lg * 4] = pk.v;
    }
    psum += __shfl_xor(psum, 16);
    psum += __shfl_xor(psum, 32);
    l_s = l_s * corr + psum;
    m_s = m_new;
    const float cc0 = __shfl(corr, lg * 4 + 0);
    const float cc1 = __shfl(corr, lg * 4 + 1);
    const float cc2 = __shfl(corr, lg * 4 + 2);
    const float cc3 = __shfl(corr, lg * 4 + 3);
#pragma unroll
    for (int dt = 0; dt < 8; ++dt) {
      yacc[dt][0] *= cc0; yacc[dt][1] *= cc1;
      yacc[dt][2] *= cc2; yacc[dt][3] *= cc3;
    }
    // this wave's V[t] DMA retired (K[t+1] stays in flight) + P writes drained
    if (t < qt) asm volatile("s_waitcnt vmcnt(4)" ::: "memory");
    else        asm volatile("s_waitcnt vmcnt(0)" ::: "memory");
    asm volatile("s_waitcnt lgkmcnt(0)" ::: "memory");
    __builtin_amdgcn_s_barrier();   // barrier B: all waves' V[t] + P in LDS
    cfence();

    // PV: y[q][d] += P[q][k] V[k][d]
#pragma unroll
    for (int kc = 0; kc < 2; ++kc) {
      const short8 pf = *(const short8*)&Pl[w][lr][kc * 32 + lg * 8];
#pragma unroll
      for (int dt = 0; dt < 8; ++dt) {
        const int d = dt * 16 + lr;
        const int off = d * 128 + ((kc * 64 + lg * 16) ^ xk);
        const short8 vf = *(const short8*)((const char*)VlC + off);
        yacc[dt] = mfma16(pf, vf, yacc[dt]);
      }
    }
    cfence();
    if (t < qt) {   // stage V[t+1] into other V buffer; hides under next QK+softmax
      const long vo = (long)(t + 1) * 64;
      ushort_t* VlN = &Vl[(t + 1) & 1][0];
#pragma unroll
      for (int i = 0; i < 4; ++i) async16(vg[i] + vo, &VlN[ld[i]]);
    }
  }

  const float linv = 1.f / l_s;
  const float i0 = __shfl(linv, lg * 4 + 0);
  const float i1 = __shfl(linv, lg * 4 + 1);
  const float i2 = __shfl(linv, lg * 4 + 2);
  const float i3 = __shfl(linv, lg * 4 + 3);
  ushort_t* yp = Y + ((long)(b * 1024 + qrow)) * 2048 + h * 128 + lr;
#pragma unroll
  for (int dt = 0; dt < 8; ++dt) {
    yp[(long)(lg * 4 + 0) * 2048 + dt * 16] = f2bf(yacc[dt][0] * i0);
    yp[(long)(lg * 4 + 1) * 2048 + dt * 16] = f2bf(yacc[dt][1] * i1);
    yp[(long)(lg * 4 + 2) * 2048 + dt * 16] = f2bf(yacc[dt][2] * i2);
    yp[(long)(lg * 4 + 3) * 2048 + dt * 16] = f2bf(yacc[dt][3] * i3);
  }
}

// ---------------- launch ----------------
extern "C" void kernel_launch(void* const* d_in, const int* in_sizes, int n_in,
                              void* d_out, int out_size, void* d_ws, size_t ws_size,
                              hipStream_t stream)
{
  (void)in_sizes; (void)n_in; (void)out_size;
  const float* x   = (const float*)d_in[0];
  const float* Wq  = (const float*)d_in[1];
  const float* bq  = (const float*)d_in[2];
  const float* Wkv = (const float*)d_in[3];
  const float* bkv = (const float*)d_in[4];
  const float* Wo  = (const float*)d_in[5];
  const float* bo  = (const float*)d_in[6];
  float* out = (float*)d_out;
  char* ws = (char*)d_ws;

  if (ws_size < 104857600) return;  // need 100 MB

  const long NX = 8192L * 2048, NWQ = 2048L * 2048, NWKV = 1024L * 2048, NWO = 2048L * 2048;
  ushort_t* xb   = (ushort_t*)(ws);              // 32MB; reused as Y after KV GEMM
  ushort_t* Qb   = (ushort_t*)(ws + 33554432);   // 32MB
  ushort_t* KVb  = (ushort_t*)(ws + 67108864);   // 16MB
  ushort_t* Wqb  = (ushort_t*)(ws + 83886080);   // 8MB; reused as Vt after Q GEMM
  ushort_t* Wkvb = (ushort_t*)(ws + 92274688);   // 4MB
  ushort_t* Wob  = (ushort_t*)(ws + 96468992);   // 8MB
  ushort_t* Vtb  = Wqb;
  ushort_t* Yb   = xb;

  k_f2bf<<<dim3(NX   / 2048), 256, 0, stream>>>(x,   xb,   NX);
  k_f2bf<<<dim3(NWQ  / 2048), 256, 0, stream>>>(Wq,  Wqb,  NWQ);
  k_f2bf<<<dim3(NWKV / 2048), 256, 0, stream>>>(Wkv, Wkvb, NWKV);
  k_f2bf<<<dim3(NWO  / 2048), 256, 0, stream>>>(Wo,  Wob,  NWO);

  const float scale = 0.08838834764831845f;  // 1/sqrt(128), folded into Q
  k_gemm<1><<<dim3(16, 64), 256, 0, stream>>>(xb, Wqb,  bq,  Qb,  2048, 2048, scale);
  k_gemm<1><<<dim3(8,  64), 256, 0, stream>>>(xb, Wkvb, bkv, KVb, 1024, 2048, 1.0f);
  k_transv<<<dim3(16, 4, 8), 256, 0, stream>>>(KVb, Vtb);
  k_attn<<<dim3(2048), 256, 0, stream>>>(Qb, KVb, Vtb, Yb);
  k_gemm<0><<<dim3(16, 64), 256, 0, stream>>>(Yb, Wob, bo, out, 2048, 2048, 1.0f);
}